// Round 11
// baseline (837.384 us; speedup 1.0000x reference)
//
#include <hip/hip_runtime.h>
#include <hip/hip_bf16.h>
#include <hip/hip_fp16.h>

#define NN 50000
#define EE 1600000
#define DIN 128
#define HH 256
#define DOUT 128

typedef __attribute__((ext_vector_type(8))) short short8;
typedef __attribute__((ext_vector_type(4))) float f32x4;

__device__ __forceinline__ short f2bf(float v) {
    union { float f; unsigned u; } a;
    a.f = v;
    unsigned r = a.u + 0x7fffu + ((a.u >> 16) & 1u);  // RTNE
    return (short)(r >> 16);
}
__device__ __forceinline__ float bf2f(short h) {
    union { unsigned u; float f; } a;
    a.u = ((unsigned)(unsigned short)h) << 16;
    return a.f;
}

// ---------------- CSR build ----------------

__global__ __launch_bounds__(256) void hist_kernel(const int* __restrict__ dst, int* __restrict__ deg, int E) {
    int e = blockIdx.x * 256 + threadIdx.x;
    if (e < E) atomicAdd(&deg[dst[e]], 1);
}

#define SCAN_B 256

__global__ __launch_bounds__(SCAN_B) void scan1_kernel(const int* __restrict__ deg, int* __restrict__ exc,
                                                       int* __restrict__ bsum, int n) {
    __shared__ int tmp[SCAN_B];
    int i = blockIdx.x * SCAN_B + threadIdx.x;
    int v = (i < n) ? deg[i] : 0;
    tmp[threadIdx.x] = v;
    __syncthreads();
    for (int o = 1; o < SCAN_B; o <<= 1) {
        int t = (threadIdx.x >= o) ? tmp[threadIdx.x - o] : 0;
        __syncthreads();
        tmp[threadIdx.x] += t;
        __syncthreads();
    }
    if (i < n) exc[i] = tmp[threadIdx.x] - v;
    if (threadIdx.x == SCAN_B - 1) bsum[blockIdx.x] = tmp[SCAN_B - 1];
}

__global__ __launch_bounds__(SCAN_B) void scan2_kernel(int* __restrict__ bsum, int nb) {
    __shared__ int tmp[SCAN_B];
    int v = (threadIdx.x < nb) ? bsum[threadIdx.x] : 0;
    tmp[threadIdx.x] = v;
    __syncthreads();
    for (int o = 1; o < SCAN_B; o <<= 1) {
        int t = (threadIdx.x >= o) ? tmp[threadIdx.x - o] : 0;
        __syncthreads();
        tmp[threadIdx.x] += t;
        __syncthreads();
    }
    if (threadIdx.x < nb) bsum[threadIdx.x] = tmp[threadIdx.x] - v;
}

__global__ __launch_bounds__(SCAN_B) void scan3_kernel(int* __restrict__ exc, const int* __restrict__ bsum,
                                                       int* __restrict__ cursor, int n, int E) {
    int i = blockIdx.x * SCAN_B + threadIdx.x;
    if (i < n) {
        int v = exc[i] + bsum[blockIdx.x];
        exc[i] = v;
        cursor[i] = v;
    }
    if (i == n) exc[n] = E;
}

#define NCB 256

__global__ __launch_bounds__(256) void scatter8_kernel(const int* __restrict__ src, const int* __restrict__ dst,
                                                       int* __restrict__ cursor, int* __restrict__ es, int E, int n) {
    int q = blockIdx.x & 7;
    int cb = blockIdx.x >> 3;
    int lo = q * (n >> 3);
    int hi = (q == 7) ? n : lo + (n >> 3);
    int chunk = (E + NCB - 1) / NCB;
    int e1 = min((cb + 1) * chunk, E);
    for (int e = cb * chunk + threadIdx.x; e < e1; e += 256) {
        int d = dst[e];
        if (d >= lo && d < hi) {
            int pos = atomicAdd(&cursor[d], 1);
            es[pos] = src[e];
        }
    }
}

// ---------------- W pre-split ----------------

__global__ __launch_bounds__(256) void wsplit_kernel(const float* __restrict__ W, short* __restrict__ WhT,
                                                     short* __restrict__ WlT, int K, int C) {
    int f = blockIdx.x * 256 + threadIdx.x;
    if (f >= K * C) return;
    int k = f / C, c = f % C;
    float v = W[f];
    short h = f2bf(v);
    short l = f2bf(v - bf2f(h));
    WhT[(size_t)c * K + k] = h;
    WlT[(size_t)c * K + k] = l;
}

// ---------------- fp32 -> fp16 table convert ----------------

__global__ __launch_bounds__(256) void tohalf_kernel(const float* __restrict__ in, __half* __restrict__ out,
                                                     size_t cnt) {
    size_t i = (size_t)(blockIdx.x * 256 + threadIdx.x) * 4;
    if (i + 3 < cnt) {
        float4 v = *(const float4*)(in + i);
        __half h0 = __float2half(v.x), h1 = __float2half(v.y);
        __half h2 = __float2half(v.z), h3 = __float2half(v.w);
        __half2* op = (__half2*)(out + i);
        op[0] = __half2(h0, h1);
        op[1] = __half2(h2, h3);
    }
}

// ---------------- split-bf16 MFMA GEMM (+fused dots; fp32 or fp16 A-in; fp32 or fp16 out) ----------------

template <bool BRELU, bool DOTS, bool HOUT, bool AHIN>
__global__ __launch_bounds__(256) void gemm_mfma_kernel(const float* __restrict__ X, const short* __restrict__ BhT,
                                                        const short* __restrict__ BlT, const float* __restrict__ bias,
                                                        float* __restrict__ out, const float* __restrict__ a1v,
                                                        const float* __restrict__ a2v, float* __restrict__ s1,
                                                        float* __restrict__ s2, int n, int K, int Cout) {
    __shared__ short Ah[128][40], Al[128][40];
    __shared__ short Bh[128][40], Bl[128][40];
    int tid = threadIdx.x;
    int row0 = blockIdx.y * 128, col0 = blockIdx.x * 128;
    int lane = tid & 63, wid = tid >> 6;
    int wr = (wid >> 1) * 64, wc = (wid & 1) * 64;

    f32x4 acc[4][4];
#pragma unroll
    for (int mi = 0; mi < 4; ++mi)
#pragma unroll
        for (int ni = 0; ni < 4; ++ni) acc[mi][ni] = 0.f;

    int srow = tid >> 1;
    int sk = (tid & 1) * 16;

    for (int k0 = 0; k0 < K; k0 += 32) {
        {
            float v[16];
            int gr = row0 + srow;
            if (gr < n) {
                if (AHIN) {
                    const __half* p = (const __half*)X + (size_t)gr * K + k0 + sk;
                    uint4 r0 = ((const uint4*)p)[0];
                    uint4 r1 = ((const uint4*)p)[1];
                    unsigned w[8] = {r0.x, r0.y, r0.z, r0.w, r1.x, r1.y, r1.z, r1.w};
#pragma unroll
                    for (int j = 0; j < 8; ++j) {
                        union { unsigned u; __half2 h; } c;
                        c.u = w[j];
                        float2 f = __half22float2(c.h);
                        v[2 * j] = f.x;
                        v[2 * j + 1] = f.y;
                    }
                } else {
                    const float* p = X + (size_t)gr * K + k0 + sk;
                    float4 f0 = ((const float4*)p)[0];
                    float4 f1 = ((const float4*)p)[1];
                    float4 f2 = ((const float4*)p)[2];
                    float4 f3 = ((const float4*)p)[3];
                    v[0] = f0.x; v[1] = f0.y; v[2] = f0.z; v[3] = f0.w;
                    v[4] = f1.x; v[5] = f1.y; v[6] = f1.z; v[7] = f1.w;
                    v[8] = f2.x; v[9] = f2.y; v[10] = f2.z; v[11] = f2.w;
                    v[12] = f3.x; v[13] = f3.y; v[14] = f3.z; v[15] = f3.w;
                }
            } else {
#pragma unroll
                for (int j = 0; j < 16; ++j) v[j] = 0.f;
            }
            short8 h0, h1, l0, l1;
#pragma unroll
            for (int j = 0; j < 8; ++j) {
                short h = f2bf(v[j]);
                h0[j] = h;
                l0[j] = f2bf(v[j] - bf2f(h));
            }
#pragma unroll
            for (int j = 0; j < 8; ++j) {
                short h = f2bf(v[8 + j]);
                h1[j] = h;
                l1[j] = f2bf(v[8 + j] - bf2f(h));
            }
            *(short8*)&Ah[srow][sk] = h0;
            *(short8*)&Ah[srow][sk + 8] = h1;
            *(short8*)&Al[srow][sk] = l0;
            *(short8*)&Al[srow][sk + 8] = l1;
        }
        {
            const short* ph = BhT + (size_t)(col0 + srow) * K + k0 + sk;
            const short* pl = BlT + (size_t)(col0 + srow) * K + k0 + sk;
            short8 bh0 = ((const short8*)ph)[0];
            short8 bh1 = ((const short8*)ph)[1];
            short8 bl0 = ((const short8*)pl)[0];
            short8 bl1 = ((const short8*)pl)[1];
            *(short8*)&Bh[srow][sk] = bh0;
            *(short8*)&Bh[srow][sk + 8] = bh1;
            *(short8*)&Bl[srow][sk] = bl0;
            *(short8*)&Bl[srow][sk + 8] = bl1;
        }
        __syncthreads();

        int fr = lane & 15, kb = lane >> 4;
        short8 a_h[4], a_l[4];
#pragma unroll
        for (int mi = 0; mi < 4; ++mi) {
            a_h[mi] = *(const short8*)&Ah[wr + mi * 16 + fr][kb * 8];
            a_l[mi] = *(const short8*)&Al[wr + mi * 16 + fr][kb * 8];
        }
#pragma unroll
        for (int ni = 0; ni < 4; ++ni) {
            short8 b_h = *(const short8*)&Bh[wc + ni * 16 + fr][kb * 8];
            short8 b_l = *(const short8*)&Bl[wc + ni * 16 + fr][kb * 8];
#pragma unroll
            for (int mi = 0; mi < 4; ++mi) {
                acc[mi][ni] = __builtin_amdgcn_mfma_f32_16x16x32_bf16(a_l[mi], b_h, acc[mi][ni], 0, 0, 0);
                acc[mi][ni] = __builtin_amdgcn_mfma_f32_16x16x32_bf16(a_h[mi], b_l, acc[mi][ni], 0, 0, 0);
                acc[mi][ni] = __builtin_amdgcn_mfma_f32_16x16x32_bf16(a_h[mi], b_h, acc[mi][ni], 0, 0, 0);
            }
        }
        __syncthreads();
    }

    int dc = lane & 15, dr = (lane >> 4) * 4;

    if (DOTS) {
#pragma unroll
        for (int mi = 0; mi < 4; ++mi) {
#pragma unroll
            for (int r = 0; r < 4; ++r) {
                float p1 = 0.f, p2 = 0.f;
#pragma unroll
                for (int ni = 0; ni < 4; ++ni) {
                    int gcol = col0 + wc + ni * 16 + dc;
                    float v = acc[mi][ni][r];
                    p1 = fmaf(v, a1v[gcol], p1);
                    p2 = fmaf(v, a2v[gcol], p2);
                }
#pragma unroll
                for (int o = 8; o; o >>= 1) {
                    p1 += __shfl_xor(p1, o, 64);
                    p2 += __shfl_xor(p2, o, 64);
                }
                int grow = row0 + wr + mi * 16 + dr + r;
                if (dc == 0 && grow < n) {
                    atomicAdd(s1 + grow, p1);
                    atomicAdd(s2 + grow, p2);
                }
            }
        }
    }

#pragma unroll
    for (int mi = 0; mi < 4; ++mi) {
#pragma unroll
        for (int r = 0; r < 4; ++r) {
            int grow = row0 + wr + mi * 16 + dr + r;
            if (grow >= n) continue;
#pragma unroll
            for (int ni = 0; ni < 4; ++ni) {
                int gcol = col0 + wc + ni * 16 + dc;
                float v = acc[mi][ni][r];
                if (BRELU) {
                    v += bias[gcol];
                    v = fmaxf(v, 0.f);
                }
                if (HOUT) {
                    ((__half*)out)[(size_t)grow * Cout + gcol] = __float2half(v);
                } else {
                    out[(size_t)grow * Cout + gcol] = v;
                }
            }
        }
    }
}

// ---------------- per-row dual dot (layer-1 only) ----------------

__global__ __launch_bounds__(256) void rowdots_kernel(const float* __restrict__ H, const float* __restrict__ a1,
                                                      const float* __restrict__ a2, float* __restrict__ s1,
                                                      float* __restrict__ s2, int n, int C) {
    int w = (blockIdx.x * 256 + threadIdx.x) >> 6;
    int lane = threadIdx.x & 63;
    if (w >= n) return;
    const float* hp = H + (size_t)w * C;
    float acc1 = 0.f, acc2 = 0.f;
    for (int c = lane; c < C; c += 64) {
        float hv = hp[c];
        acc1 = fmaf(hv, a1[c], acc1);
        acc2 = fmaf(hv, a2[c], acc2);
    }
#pragma unroll
    for (int o = 32; o; o >>= 1) {
        acc1 += __shfl_xor(acc1, o, 64);
        acc2 += __shfl_xor(acc2, o, 64);
    }
    if (lane == 0) {
        s1[w] = acc1;
        s2[w] = acc2;
    }
}

// ---------------- softmax prep -> packed (src, alpha) records + invden ----------------

__global__ __launch_bounds__(256) void mdenp_kernel(const float* __restrict__ ssrc, const float* __restrict__ sdst,
                                                    const int* __restrict__ off, const int* __restrict__ es,
                                                    uint2* __restrict__ pae, float* __restrict__ invden, int n) {
    int w = (blockIdx.x * 256 + threadIdx.x) >> 6;
    int lane = threadIdx.x & 63;
    if (w >= n) return;
    int beg = off[w], end = off[w + 1];
    float sd = sdst[w];
    float m = -3e38f;
    for (int e = beg + lane; e < end; e += 64) {
        float g = ssrc[es[e]] + sd;
        g = (g > 0.f) ? g : 0.2f * g;
        m = fmaxf(m, g);
    }
#pragma unroll
    for (int o = 32; o; o >>= 1) m = fmaxf(m, __shfl_xor(m, o, 64));
    float den = 0.f;
    for (int e = beg + lane; e < end; e += 64) {
        int s = es[e];
        float g = ssrc[s] + sd;
        g = (g > 0.f) ? g : 0.2f * g;
        float p = __expf(g - m);
        den += p;
        pae[e] = make_uint2((unsigned)s, __float_as_uint(p));
    }
#pragma unroll
    for (int o = 32; o; o >>= 1) den += __shfl_xor(den, o, 64);
    if (lane == 0) invden[w] = (den > 0.f) ? 1.f / den : 0.f;
}

// ---------------- col-sliced L2-resident aggregation: 32 cols/pass, pass-major blocks ----------------
// Per pass the hot H window is n*64B = 3.2MB (< 4MB per-XCD L2). 16 lanes per edge-row (half2 each),
// 4 edge groups per wave. One wave per node per pass.

template <int C, bool RELU, bool OUTH>
__global__ __launch_bounds__(256) void aggs_kernel(const __half* __restrict__ H, const uint2* __restrict__ pae,
                                                   const float* __restrict__ invden, const int* __restrict__ off,
                                                   const float* __restrict__ bias, void* __restrict__ out, int n,
                                                   int chunks) {
    int pass = blockIdx.x / chunks;
    int chunk = blockIdx.x % chunks;
    int wid = threadIdx.x >> 6, lane = threadIdx.x & 63;
    int node = chunk * 4 + wid;
    if (node >= n) return;
    int beg = off[node], end = off[node + 1];
    int g = lane >> 4, cl = lane & 15;
    int col = pass * 32 + cl * 2;
    const __half2* Hc = (const __half2*)(H + col);

    float a0 = 0.f, a1 = 0.f;
    for (int base = beg; base < end; base += 64) {
        int e = base + lane;
        float al = 0.f;
        int s = 0;
        if (e < end) {
            uint2 r = pae[e];
            s = (int)r.x;
            al = __uint_as_float(r.y);
        }
        int cnt = end - base;
        if (cnt > 64) cnt = 64;
        int j0 = 0;
        for (; j0 + 16 <= cnt; j0 += 16) {
            float pj[4];
            const __half2* hp[4];
#pragma unroll
            for (int u = 0; u < 4; ++u) {
                int j = j0 + u * 4 + g;
                pj[u] = __shfl(al, j, 64);
                int sj = __shfl(s, j, 64);
                hp[u] = Hc + (size_t)sj * (C / 2);
            }
            __half2 hv[4];
#pragma unroll
            for (int u = 0; u < 4; ++u) hv[u] = *hp[u];
#pragma unroll
            for (int u = 0; u < 4; ++u) {
                float2 f = __half22float2(hv[u]);
                a0 = fmaf(pj[u], f.x, a0);
                a1 = fmaf(pj[u], f.y, a1);
            }
        }
        for (; j0 < cnt; j0 += 4) {
            int j = j0 + g;
            bool ok = j < cnt;
            int jj = ok ? j : cnt - 1;
            float pj = __shfl(al, jj, 64);
            if (!ok) pj = 0.f;
            int sj = __shfl(s, jj, 64);
            float2 f = __half22float2(Hc[(size_t)sj * (C / 2)]);
            a0 = fmaf(pj, f.x, a0);
            a1 = fmaf(pj, f.y, a1);
        }
    }

    // combine the 4 edge groups (lanes with same cl)
    a0 += __shfl_xor(a0, 16, 64);
    a1 += __shfl_xor(a1, 16, 64);
    a0 += __shfl_xor(a0, 32, 64);
    a1 += __shfl_xor(a1, 32, 64);

    if (g == 0) {
        float inv = invden[node];
        float b0 = bias ? bias[col] : 0.f;
        float b1 = bias ? bias[col + 1] : 0.f;
        float o0 = fmaf(a0, inv, b0);
        float o1 = fmaf(a1, inv, b1);
        if (RELU) {
            o0 = fmaxf(o0, 0.f);
            o1 = fmaxf(o1, 0.f);
        }
        if (OUTH) {
            *((__half2*)((__half*)out + (size_t)node * C + col)) = __half2(__float2half(o0), __float2half(o1));
        } else {
            *((float2*)((float*)out + (size_t)node * C + col)) = make_float2(o0, o1);
        }
    }
}

// ---------------- fused aggregation (layers 1 & 4): softmax prep + 8B/lane gather, 1 wave/node ----------------

template <int C, bool RELU, bool SOFTMAX, bool OUTH>
__global__ __launch_bounds__(256) void aggf_kernel(const __half* __restrict__ H, const float* __restrict__ ssrc,
                                                   const float* __restrict__ sdst, const int* __restrict__ off,
                                                   const int* __restrict__ es, const float* __restrict__ bias,
                                                   float* __restrict__ out, int n) {
    constexpr int VPL = C / 64;
    int wid = threadIdx.x >> 6, lane = threadIdx.x & 63;
    int node = blockIdx.x * 4 + wid;
    if (node >= n) return;
    int beg = off[node], end = off[node + 1];
    float sd = sdst[node];

    float m = -3e38f;
    for (int e = beg + lane; e < end; e += 64) {
        float g = ssrc[es[e]] + sd;
        g = (g > 0.f) ? g : 0.2f * g;
        m = fmaxf(m, g);
    }
#pragma unroll
    for (int o = 32; o; o >>= 1) m = fmaxf(m, __shfl_xor(m, o, 64));

    float acc[VPL];
#pragma unroll
    for (int v = 0; v < VPL; ++v) acc[v] = 0.f;
    float den = 0.f;
    int c0 = lane * VPL;

    for (int base = beg; base < end; base += 64) {
        int e = base + lane;
        float p = 0.f;
        int s = 0;
        if (e < end) {
            s = es[e];
            float g = ssrc[s] + sd;
            g = (g > 0.f) ? g : 0.2f * g;
            p = __expf(g - m);
            den += p;
        }
        int cnt = end - base;
        if (cnt > 64) cnt = 64;
        int j0 = 0;
        for (; j0 + 8 <= cnt; j0 += 8) {
            float pj[8];
            const __half* hp[8];
#pragma unroll
            for (int u = 0; u < 8; ++u) {
                pj[u] = __shfl(p, j0 + u, 64);
                int sj = __shfl(s, j0 + u, 64);
                hp[u] = H + (size_t)sj * C + c0;
            }
            if (VPL == 4) {
                uint2 raw[8];
#pragma unroll
                for (int u = 0; u < 8; ++u) raw[u] = *(const uint2*)hp[u];
#pragma unroll
                for (int u = 0; u < 8; ++u) {
                    union { unsigned u32; __half2 h2; } lo, hi;
                    lo.u32 = raw[u].x;
                    hi.u32 = raw[u].y;
                    float2 f0 = __half22float2(lo.h2);
                    float2 f1 = __half22float2(hi.h2);
                    acc[0] = fmaf(pj[u], f0.x, acc[0]);
                    acc[1] = fmaf(pj[u], f0.y, acc[1]);
                    acc[2] = fmaf(pj[u], f1.x, acc[2]);
                    acc[3] = fmaf(pj[u], f1.y, acc[3]);
                }
            } else {
                __half2 hv[8];
#pragma unroll
                for (int u = 0; u < 8; ++u) hv[u] = *(const __half2*)hp[u];
#pragma unroll
                for (int u = 0; u < 8; ++u) {
                    float2 f = __half22float2(hv[u]);
                    acc[0] = fmaf(pj[u], f.x, acc[0]);
                    acc[1] = fmaf(pj[u], f.y, acc[1]);
                }
            }
        }
        for (; j0 < cnt; ++j0) {
            float pj = __shfl(p, j0, 64);
            int sj = __shfl(s, j0, 64);
            const __half* hp = H + (size_t)sj * C + c0;
            if (VPL == 4) {
                uint2 raw = *(const uint2*)hp;
                union { unsigned u32; __half2 h2; } lo, hi;
                lo.u32 = raw.x;
                hi.u32 = raw.y;
                float2 f0 = __half22float2(lo.h2);
                float2 f1 = __half22float2(hi.h2);
                acc[0] = fmaf(pj, f0.x, acc[0]);
                acc[1] = fmaf(pj, f0.y, acc[1]);
                acc[2] = fmaf(pj, f1.x, acc[2]);
                acc[3] = fmaf(pj, f1.y, acc[3]);
            } else {
                float2 f = __half22float2(*(const __half2*)hp);
                acc[0] = fmaf(pj, f.x, acc[0]);
                acc[1] = fmaf(pj, f.y, acc[1]);
            }
        }
    }

#pragma unroll
    for (int o = 32; o; o >>= 1) den += __shfl_xor(den, o, 64);
    float inv = (den > 0.f) ? 1.f / den : 0.f;

    float ov[VPL];
#pragma unroll
    for (int v = 0; v < VPL; ++v) {
        float bb = bias ? bias[c0 + v] : 0.f;
        ov[v] = fmaf(acc[v], inv, bb);
        if (RELU) ov[v] = fmaxf(ov[v], 0.f);
    }
    if (SOFTMAX) {
        float mm = ov[0];
#pragma unroll
        for (int v = 1; v < VPL; ++v) mm = fmaxf(mm, ov[v]);
#pragma unroll
        for (int o = 32; o; o >>= 1) mm = fmaxf(mm, __shfl_xor(mm, o, 64));
        float ss = 0.f;
#pragma unroll
        for (int v = 0; v < VPL; ++v) {
            ov[v] = __expf(ov[v] - mm);
            ss += ov[v];
        }
#pragma unroll
        for (int o = 32; o; o >>= 1) ss += __shfl_xor(ss, o, 64);
        float si = 1.f / ss;
#pragma unroll
        for (int v = 0; v < VPL; ++v) ov[v] *= si;
    }
    if (OUTH) {
        __half* op = (__half*)out + (size_t)node * C + c0;
        if (VPL == 4) {
            union { __half2 h2; unsigned u; } w0, w1;
            w0.h2 = __half2(__float2half(ov[0]), __float2half(ov[1]));
            w1.h2 = __half2(__float2half(ov[2]), __float2half(ov[3]));
            uint2 pk;
            pk.x = w0.u;
            pk.y = w1.u;
            *(uint2*)op = pk;
        } else {
            *(__half2*)op = __half2(__float2half(ov[0]), __float2half(ov[1]));
        }
    } else {
        float* op = out + (size_t)node * C + c0;
        if (VPL == 4)
            *(float4*)op = make_float4(ov[0], ov[1], ov[2], ov[3]);
        else
            *(float2*)op = make_float2(ov[0], ov[1]);
    }
}

// ---------------- launch ----------------

extern "C" void kernel_launch(void* const* d_in, const int* in_sizes, int n_in,
                              void* d_out, int out_size, void* d_ws, size_t ws_size,
                              hipStream_t stream) {
    const float* x = (const float*)d_in[0];
    const int* ei = (const int*)d_in[1];
    const float* W1 = (const float*)d_in[2];
    const float* a1s = (const float*)d_in[3];
    const float* a1d = (const float*)d_in[4];
    const float* b1 = (const float*)d_in[5];
    const float* W2 = (const float*)d_in[6];
    const float* a2s = (const float*)d_in[7];
    const float* a2d = (const float*)d_in[8];
    const float* b2 = (const float*)d_in[9];
    const float* W3 = (const float*)d_in[10];
    const float* a3s = (const float*)d_in[11];
    const float* a3d = (const float*)d_in[12];
    const float* b3 = (const float*)d_in[13];

    const int n = NN, E = EE;
    const int* src = ei;
    const int* dst = ei + E;

    char* base = (char*)d_ws;
    size_t o = 0;
    auto alloc = [&](size_t bytes) -> char* {
        char* p = base + o;
        o += (bytes + 255) & ~(size_t)255;
        return p;
    };
    int* off = (int*)alloc((n + 1) * sizeof(int));
    int* cur = (int*)alloc((n + 1) * sizeof(int));
    int* bsum = (int*)alloc(1024 * sizeof(int));
    int* es = (int*)alloc((size_t)E * sizeof(int));
    uint2* pae = (uint2*)alloc((size_t)E * sizeof(uint2));
    float* sbuf = (float*)alloc((size_t)2 * n * sizeof(float));  // ssrc | sdst
    float* ssrc = sbuf;
    float* sdst = sbuf + n;
    float* invden = (float*)alloc((size_t)n * sizeof(float));
    float* was = (float*)alloc(256 * sizeof(float));
    float* wad = (float*)alloc(256 * sizeof(float));
    short* W1h = (short*)alloc((size_t)DIN * HH * sizeof(short));
    short* W1l = (short*)alloc((size_t)DIN * HH * sizeof(short));
    short* W2h = (short*)alloc((size_t)HH * HH * sizeof(short));
    short* W2l = (short*)alloc((size_t)HH * HH * sizeof(short));
    short* W3h = (short*)alloc((size_t)HH * DOUT * sizeof(short));
    short* W3l = (short*)alloc((size_t)HH * DOUT * sizeof(short));
    __half* xh = (__half*)alloc((size_t)n * DIN * sizeof(__half));
    __half* Hh = (__half*)alloc((size_t)n * HH * sizeof(__half));
    __half* Abuf = (__half*)alloc((size_t)n * HH * sizeof(__half));  // fp16 inter-layer activations
    float* Hbuf = (float*)alloc((size_t)n * DIN * sizeof(float));    // layer-1 Z (fp32, C=128)
    (void)ws_size;

    // --- CSR build (grouped by dst) ---
    hipMemsetAsync(cur, 0, (n + 1) * sizeof(int), stream);
    hist_kernel<<<(E + 255) / 256, 256, 0, stream>>>(dst, cur, E);
    int nb = (n + SCAN_B - 1) / SCAN_B;
    scan1_kernel<<<nb, SCAN_B, 0, stream>>>(cur, off, bsum, n);
    scan2_kernel<<<1, SCAN_B, 0, stream>>>(bsum, nb);
    scan3_kernel<<<nb, SCAN_B, 0, stream>>>(off, bsum, cur, n, E);
    scatter8_kernel<<<NCB * 8, 256, 0, stream>>>(src, dst, cur, es, E, n);

    // --- W splits + X fp16 copy ---
    wsplit_kernel<<<(DIN * HH + 255) / 256, 256, 0, stream>>>(W1, W1h, W1l, DIN, HH);
    wsplit_kernel<<<(HH * HH + 255) / 256, 256, 0, stream>>>(W2, W2h, W2l, HH, HH);
    wsplit_kernel<<<(HH * DOUT + 255) / 256, 256, 0, stream>>>(W3, W3h, W3l, HH, DOUT);
    tohalf_kernel<<<((n * DIN / 4) + 255) / 256, 256, 0, stream>>>(x, xh, (size_t)n * DIN);

    int wgrid = (n * 64 + 255) / 256;
    int agrid = (n + 3) / 4;  // also the aggs chunk count
    int rb = (n + 127) / 128;

    // --- layer 1, reordered: logits via X@(W1 a); Z = A-hat X (fp16 gather, C=128); A1 = relu(Z W1 + b1) -> fp16 ---
    {
        rowdots_kernel<<<(128 * 64 + 255) / 256, 256, 0, stream>>>(W1, a1s, a1d, was, wad, DIN, HH);
        rowdots_kernel<<<wgrid, 256, 0, stream>>>(x, was, wad, ssrc, sdst, n, DIN);
        aggf_kernel<DIN, false, false, false><<<agrid, 256, 0, stream>>>(xh, ssrc, sdst, off, es, nullptr, Hbuf, n);
        dim3 g(HH / 128, rb);
        gemm_mfma_kernel<true, false, true, false><<<g, 256, 0, stream>>>(Hbuf, W1h, W1l, b1, (float*)Abuf, nullptr,
                                                                          nullptr, nullptr, nullptr, n, DIN, HH);
    }
    // --- layers 2,3 (shared W2): gemm(+dots) -> Hh; mdenp -> (src,alpha)+invden; col-sliced L2 agg -> Abuf fp16 ---
    for (int t = 0; t < 2; ++t) {
        dim3 g(HH / 128, rb);
        hipMemsetAsync(sbuf, 0, (size_t)2 * n * sizeof(float), stream);
        gemm_mfma_kernel<false, true, true, true><<<g, 256, 0, stream>>>((const float*)Abuf, W2h, W2l, nullptr,
                                                                         (float*)Hh, a2s, a2d, ssrc, sdst, n, HH, HH);
        mdenp_kernel<<<wgrid, 256, 0, stream>>>(ssrc, sdst, off, es, pae, invden, n);
        aggs_kernel<HH, true, true><<<(HH / 32) * agrid, 256, 0, stream>>>(Hh, pae, invden, off, b2, (void*)Abuf, n,
                                                                           agrid);
    }
    // --- layer 4: gemm(+dots) -> Hh; fused agg + in-wave feature softmax -> d_out (fp32) ---
    {
        dim3 g(DOUT / 128, rb);
        hipMemsetAsync(sbuf, 0, (size_t)2 * n * sizeof(float), stream);
        gemm_mfma_kernel<false, true, true, true><<<g, 256, 0, stream>>>((const float*)Abuf, W3h, W3l, nullptr,
                                                                         (float*)Hh, a3s, a3d, ssrc, sdst, n, HH,
                                                                         DOUT);
        aggf_kernel<DOUT, false, true, false><<<agrid, 256, 0, stream>>>(Hh, ssrc, sdst, off, es, b3, (float*)d_out,
                                                                         n);
    }
}

// Round 12
// 666.313 us; speedup vs baseline: 1.2567x; 1.2567x over previous
//
#include <hip/hip_runtime.h>
#include <hip/hip_bf16.h>
#include <hip/hip_fp16.h>

#define NN 50000
#define EE 1600000
#define DIN 128
#define HH 256
#define DOUT 128

typedef __attribute__((ext_vector_type(8))) short short8;
typedef __attribute__((ext_vector_type(4))) float f32x4;

__device__ __forceinline__ short f2bf(float v) {
    union { float f; unsigned u; } a;
    a.f = v;
    unsigned r = a.u + 0x7fffu + ((a.u >> 16) & 1u);  // RTNE
    return (short)(r >> 16);
}
__device__ __forceinline__ float bf2f(short h) {
    union { unsigned u; float f; } a;
    a.u = ((unsigned)(unsigned short)h) << 16;
    return a.f;
}

// ---------------- CSR build ----------------

__global__ __launch_bounds__(256) void hist_kernel(const int* __restrict__ dst, int* __restrict__ deg, int E) {
    int e = blockIdx.x * 256 + threadIdx.x;
    if (e < E) atomicAdd(&deg[dst[e]], 1);
}

#define SCAN_B 256

__global__ __launch_bounds__(SCAN_B) void scan1_kernel(const int* __restrict__ deg, int* __restrict__ exc,
                                                       int* __restrict__ bsum, int n) {
    __shared__ int tmp[SCAN_B];
    int i = blockIdx.x * SCAN_B + threadIdx.x;
    int v = (i < n) ? deg[i] : 0;
    tmp[threadIdx.x] = v;
    __syncthreads();
    for (int o = 1; o < SCAN_B; o <<= 1) {
        int t = (threadIdx.x >= o) ? tmp[threadIdx.x - o] : 0;
        __syncthreads();
        tmp[threadIdx.x] += t;
        __syncthreads();
    }
    if (i < n) exc[i] = tmp[threadIdx.x] - v;
    if (threadIdx.x == SCAN_B - 1) bsum[blockIdx.x] = tmp[SCAN_B - 1];
}

__global__ __launch_bounds__(SCAN_B) void scan2_kernel(int* __restrict__ bsum, int nb) {
    __shared__ int tmp[SCAN_B];
    int v = (threadIdx.x < nb) ? bsum[threadIdx.x] : 0;
    tmp[threadIdx.x] = v;
    __syncthreads();
    for (int o = 1; o < SCAN_B; o <<= 1) {
        int t = (threadIdx.x >= o) ? tmp[threadIdx.x - o] : 0;
        __syncthreads();
        tmp[threadIdx.x] += t;
        __syncthreads();
    }
    if (threadIdx.x < nb) bsum[threadIdx.x] = tmp[threadIdx.x] - v;
}

__global__ __launch_bounds__(SCAN_B) void scan3_kernel(int* __restrict__ exc, const int* __restrict__ bsum,
                                                       int* __restrict__ cursor, int n, int E) {
    int i = blockIdx.x * SCAN_B + threadIdx.x;
    if (i < n) {
        int v = exc[i] + bsum[blockIdx.x];
        exc[i] = v;
        cursor[i] = v;
    }
    if (i == n) exc[n] = E;
}

#define NCB 256

__global__ __launch_bounds__(256) void scatter8_kernel(const int* __restrict__ src, const int* __restrict__ dst,
                                                       int* __restrict__ cursor, int* __restrict__ es, int E, int n) {
    int q = blockIdx.x & 7;
    int cb = blockIdx.x >> 3;
    int lo = q * (n >> 3);
    int hi = (q == 7) ? n : lo + (n >> 3);
    int chunk = (E + NCB - 1) / NCB;
    int e1 = min((cb + 1) * chunk, E);
    for (int e = cb * chunk + threadIdx.x; e < e1; e += 256) {
        int d = dst[e];
        if (d >= lo && d < hi) {
            int pos = atomicAdd(&cursor[d], 1);
            es[pos] = src[e];
        }
    }
}

// ---------------- W pre-split ----------------

__global__ __launch_bounds__(256) void wsplit_kernel(const float* __restrict__ W, short* __restrict__ WhT,
                                                     short* __restrict__ WlT, int K, int C) {
    int f = blockIdx.x * 256 + threadIdx.x;
    if (f >= K * C) return;
    int k = f / C, c = f % C;
    float v = W[f];
    short h = f2bf(v);
    short l = f2bf(v - bf2f(h));
    WhT[(size_t)c * K + k] = h;
    WlT[(size_t)c * K + k] = l;
}

// ---------------- fp32 -> fp16 table convert ----------------

__global__ __launch_bounds__(256) void tohalf_kernel(const float* __restrict__ in, __half* __restrict__ out,
                                                     size_t cnt) {
    size_t i = (size_t)(blockIdx.x * 256 + threadIdx.x) * 4;
    if (i + 3 < cnt) {
        float4 v = *(const float4*)(in + i);
        __half h0 = __float2half(v.x), h1 = __float2half(v.y);
        __half h2 = __float2half(v.z), h3 = __float2half(v.w);
        __half2* op = (__half2*)(out + i);
        op[0] = __half2(h0, h1);
        op[1] = __half2(h2, h3);
    }
}

// ---------------- global max of ssrc (mapped-uint atomicMax) ----------------

__global__ __launch_bounds__(256) void gmax_kernel(const float* __restrict__ s, unsigned* __restrict__ gm, int n) {
    int i0 = blockIdx.x * 256 + threadIdx.x;
    float m = -3e38f;
    for (int i = i0; i < n; i += 256 * 64) m = fmaxf(m, s[i]);
#pragma unroll
    for (int o = 32; o; o >>= 1) m = fmaxf(m, __shfl_xor(m, o, 64));
    if ((threadIdx.x & 63) == 0) {
        union { float f; unsigned u; } a;
        a.f = m;
        unsigned v = (a.u & 0x80000000u) ? ~a.u : (a.u | 0x80000000u);
        atomicMax(gm, v);
    }
}

__device__ __forceinline__ float unmap_max(unsigned v) {
    unsigned u = (v & 0x80000000u) ? (v ^ 0x80000000u) : ~v;
    union { unsigned u; float f; } a;
    a.u = u;
    return a.f;
}

// ---------------- split-bf16 MFMA GEMM (+fused dots; fp32 or fp16 A-in; fp32 or fp16 out) ----------------

template <bool BRELU, bool DOTS, bool HOUT, bool AHIN>
__global__ __launch_bounds__(256) void gemm_mfma_kernel(const float* __restrict__ X, const short* __restrict__ BhT,
                                                        const short* __restrict__ BlT, const float* __restrict__ bias,
                                                        float* __restrict__ out, const float* __restrict__ a1v,
                                                        const float* __restrict__ a2v, float* __restrict__ s1,
                                                        float* __restrict__ s2, int n, int K, int Cout) {
    __shared__ short Ah[128][40], Al[128][40];
    __shared__ short Bh[128][40], Bl[128][40];
    int tid = threadIdx.x;
    int row0 = blockIdx.y * 128, col0 = blockIdx.x * 128;
    int lane = tid & 63, wid = tid >> 6;
    int wr = (wid >> 1) * 64, wc = (wid & 1) * 64;

    f32x4 acc[4][4];
#pragma unroll
    for (int mi = 0; mi < 4; ++mi)
#pragma unroll
        for (int ni = 0; ni < 4; ++ni) acc[mi][ni] = 0.f;

    int srow = tid >> 1;
    int sk = (tid & 1) * 16;

    for (int k0 = 0; k0 < K; k0 += 32) {
        {
            float v[16];
            int gr = row0 + srow;
            if (gr < n) {
                if (AHIN) {
                    const __half* p = (const __half*)X + (size_t)gr * K + k0 + sk;
                    uint4 r0 = ((const uint4*)p)[0];
                    uint4 r1 = ((const uint4*)p)[1];
                    unsigned w[8] = {r0.x, r0.y, r0.z, r0.w, r1.x, r1.y, r1.z, r1.w};
#pragma unroll
                    for (int j = 0; j < 8; ++j) {
                        union { unsigned u; __half2 h; } c;
                        c.u = w[j];
                        float2 f = __half22float2(c.h);
                        v[2 * j] = f.x;
                        v[2 * j + 1] = f.y;
                    }
                } else {
                    const float* p = X + (size_t)gr * K + k0 + sk;
                    float4 f0 = ((const float4*)p)[0];
                    float4 f1 = ((const float4*)p)[1];
                    float4 f2 = ((const float4*)p)[2];
                    float4 f3 = ((const float4*)p)[3];
                    v[0] = f0.x; v[1] = f0.y; v[2] = f0.z; v[3] = f0.w;
                    v[4] = f1.x; v[5] = f1.y; v[6] = f1.z; v[7] = f1.w;
                    v[8] = f2.x; v[9] = f2.y; v[10] = f2.z; v[11] = f2.w;
                    v[12] = f3.x; v[13] = f3.y; v[14] = f3.z; v[15] = f3.w;
                }
            } else {
#pragma unroll
                for (int j = 0; j < 16; ++j) v[j] = 0.f;
            }
            short8 h0, h1, l0, l1;
#pragma unroll
            for (int j = 0; j < 8; ++j) {
                short h = f2bf(v[j]);
                h0[j] = h;
                l0[j] = f2bf(v[j] - bf2f(h));
            }
#pragma unroll
            for (int j = 0; j < 8; ++j) {
                short h = f2bf(v[8 + j]);
                h1[j] = h;
                l1[j] = f2bf(v[8 + j] - bf2f(h));
            }
            *(short8*)&Ah[srow][sk] = h0;
            *(short8*)&Ah[srow][sk + 8] = h1;
            *(short8*)&Al[srow][sk] = l0;
            *(short8*)&Al[srow][sk + 8] = l1;
        }
        {
            const short* ph = BhT + (size_t)(col0 + srow) * K + k0 + sk;
            const short* pl = BlT + (size_t)(col0 + srow) * K + k0 + sk;
            short8 bh0 = ((const short8*)ph)[0];
            short8 bh1 = ((const short8*)ph)[1];
            short8 bl0 = ((const short8*)pl)[0];
            short8 bl1 = ((const short8*)pl)[1];
            *(short8*)&Bh[srow][sk] = bh0;
            *(short8*)&Bh[srow][sk + 8] = bh1;
            *(short8*)&Bl[srow][sk] = bl0;
            *(short8*)&Bl[srow][sk + 8] = bl1;
        }
        __syncthreads();

        int fr = lane & 15, kb = lane >> 4;
        short8 a_h[4], a_l[4];
#pragma unroll
        for (int mi = 0; mi < 4; ++mi) {
            a_h[mi] = *(const short8*)&Ah[wr + mi * 16 + fr][kb * 8];
            a_l[mi] = *(const short8*)&Al[wr + mi * 16 + fr][kb * 8];
        }
#pragma unroll
        for (int ni = 0; ni < 4; ++ni) {
            short8 b_h = *(const short8*)&Bh[wc + ni * 16 + fr][kb * 8];
            short8 b_l = *(const short8*)&Bl[wc + ni * 16 + fr][kb * 8];
#pragma unroll
            for (int mi = 0; mi < 4; ++mi) {
                acc[mi][ni] = __builtin_amdgcn_mfma_f32_16x16x32_bf16(a_l[mi], b_h, acc[mi][ni], 0, 0, 0);
                acc[mi][ni] = __builtin_amdgcn_mfma_f32_16x16x32_bf16(a_h[mi], b_l, acc[mi][ni], 0, 0, 0);
                acc[mi][ni] = __builtin_amdgcn_mfma_f32_16x16x32_bf16(a_h[mi], b_h, acc[mi][ni], 0, 0, 0);
            }
        }
        __syncthreads();
    }

    int dc = lane & 15, dr = (lane >> 4) * 4;

    if (DOTS) {
#pragma unroll
        for (int mi = 0; mi < 4; ++mi) {
#pragma unroll
            for (int r = 0; r < 4; ++r) {
                float p1 = 0.f, p2 = 0.f;
#pragma unroll
                for (int ni = 0; ni < 4; ++ni) {
                    int gcol = col0 + wc + ni * 16 + dc;
                    float v = acc[mi][ni][r];
                    p1 = fmaf(v, a1v[gcol], p1);
                    p2 = fmaf(v, a2v[gcol], p2);
                }
#pragma unroll
                for (int o = 8; o; o >>= 1) {
                    p1 += __shfl_xor(p1, o, 64);
                    p2 += __shfl_xor(p2, o, 64);
                }
                int grow = row0 + wr + mi * 16 + dr + r;
                if (dc == 0 && grow < n) {
                    atomicAdd(s1 + grow, p1);
                    atomicAdd(s2 + grow, p2);
                }
            }
        }
    }

#pragma unroll
    for (int mi = 0; mi < 4; ++mi) {
#pragma unroll
        for (int r = 0; r < 4; ++r) {
            int grow = row0 + wr + mi * 16 + dr + r;
            if (grow >= n) continue;
#pragma unroll
            for (int ni = 0; ni < 4; ++ni) {
                int gcol = col0 + wc + ni * 16 + dc;
                float v = acc[mi][ni][r];
                if (BRELU) {
                    v += bias[gcol];
                    v = fmaxf(v, 0.f);
                }
                if (HOUT) {
                    ((__half*)out)[(size_t)grow * Cout + gcol] = __float2half(v);
                } else {
                    out[(size_t)grow * Cout + gcol] = v;
                }
            }
        }
    }
}

// ---------------- per-row dual dot (layer-1 only) ----------------

__global__ __launch_bounds__(256) void rowdots_kernel(const float* __restrict__ H, const float* __restrict__ a1,
                                                      const float* __restrict__ a2, float* __restrict__ s1,
                                                      float* __restrict__ s2, int n, int C) {
    int w = (blockIdx.x * 256 + threadIdx.x) >> 6;
    int lane = threadIdx.x & 63;
    if (w >= n) return;
    const float* hp = H + (size_t)w * C;
    float acc1 = 0.f, acc2 = 0.f;
    for (int c = lane; c < C; c += 64) {
        float hv = hp[c];
        acc1 = fmaf(hv, a1[c], acc1);
        acc2 = fmaf(hv, a2[c], acc2);
    }
#pragma unroll
    for (int o = 32; o; o >>= 1) {
        acc1 += __shfl_xor(acc1, o, 64);
        acc2 += __shfl_xor(acc2, o, 64);
    }
    if (lane == 0) {
        s1[w] = acc1;
        s2[w] = acc2;
    }
}

// ---------------- fused aggregation: single-pass (shift-bound softmax) + 8B/lane gather ----------------
// m-hat = lrelu(S* + sd) >= true segment max (lrelu monotone); softmax is shift-invariant, exp
// underflow for far-below-max edges is harmless in fp32.

template <int C, bool RELU, bool SOFTMAX, bool OUTH>
__global__ __launch_bounds__(256) void aggf_kernel(const __half* __restrict__ H, const float* __restrict__ ssrc,
                                                   const float* __restrict__ sdst, const int* __restrict__ off,
                                                   const int* __restrict__ es, const float* __restrict__ bias,
                                                   float* __restrict__ out, const unsigned* __restrict__ gmu, int n) {
    constexpr int VPL = C / 64;
    int wid = threadIdx.x >> 6, lane = threadIdx.x & 63;
    int node = blockIdx.x * 4 + wid;
    if (node >= n) return;
    int beg = off[node], end = off[node + 1];
    float sd = sdst[node];
    float m = unmap_max(gmu[0]) + sd;
    m = (m > 0.f) ? m : 0.2f * m;  // m-hat

    float acc[VPL];
#pragma unroll
    for (int v = 0; v < VPL; ++v) acc[v] = 0.f;
    float den = 0.f;
    int c0 = lane * VPL;

    for (int base = beg; base < end; base += 64) {
        int e = base + lane;
        float p = 0.f;
        int s = 0;
        if (e < end) {
            s = es[e];
            float g = ssrc[s] + sd;
            g = (g > 0.f) ? g : 0.2f * g;
            p = __expf(g - m);
            den += p;
        }
        int cnt = end - base;
        if (cnt > 64) cnt = 64;
        int j0 = 0;
        for (; j0 + 8 <= cnt; j0 += 8) {
            float pj[8];
            const __half* hp[8];
#pragma unroll
            for (int u = 0; u < 8; ++u) {
                pj[u] = __shfl(p, j0 + u, 64);
                int sj = __shfl(s, j0 + u, 64);
                hp[u] = H + (size_t)sj * C + c0;
            }
            if (VPL == 4) {
                uint2 raw[8];
#pragma unroll
                for (int u = 0; u < 8; ++u) raw[u] = *(const uint2*)hp[u];
#pragma unroll
                for (int u = 0; u < 8; ++u) {
                    union { unsigned u32; __half2 h2; } lo, hi;
                    lo.u32 = raw[u].x;
                    hi.u32 = raw[u].y;
                    float2 f0 = __half22float2(lo.h2);
                    float2 f1 = __half22float2(hi.h2);
                    acc[0] = fmaf(pj[u], f0.x, acc[0]);
                    acc[1] = fmaf(pj[u], f0.y, acc[1]);
                    acc[2] = fmaf(pj[u], f1.x, acc[2]);
                    acc[3] = fmaf(pj[u], f1.y, acc[3]);
                }
            } else {
                __half2 hv[8];
#pragma unroll
                for (int u = 0; u < 8; ++u) hv[u] = *(const __half2*)hp[u];
#pragma unroll
                for (int u = 0; u < 8; ++u) {
                    float2 f = __half22float2(hv[u]);
                    acc[0] = fmaf(pj[u], f.x, acc[0]);
                    acc[1] = fmaf(pj[u], f.y, acc[1]);
                }
            }
        }
        for (; j0 < cnt; ++j0) {
            float pj = __shfl(p, j0, 64);
            int sj = __shfl(s, j0, 64);
            const __half* hp = H + (size_t)sj * C + c0;
            if (VPL == 4) {
                uint2 raw = *(const uint2*)hp;
                union { unsigned u32; __half2 h2; } lo, hi;
                lo.u32 = raw.x;
                hi.u32 = raw.y;
                float2 f0 = __half22float2(lo.h2);
                float2 f1 = __half22float2(hi.h2);
                acc[0] = fmaf(pj, f0.x, acc[0]);
                acc[1] = fmaf(pj, f0.y, acc[1]);
                acc[2] = fmaf(pj, f1.x, acc[2]);
                acc[3] = fmaf(pj, f1.y, acc[3]);
            } else {
                float2 f = __half22float2(*(const __half2*)hp);
                acc[0] = fmaf(pj, f.x, acc[0]);
                acc[1] = fmaf(pj, f.y, acc[1]);
            }
        }
    }

#pragma unroll
    for (int o = 32; o; o >>= 1) den += __shfl_xor(den, o, 64);
    float inv = (den > 0.f) ? 1.f / den : 0.f;

    float ov[VPL];
#pragma unroll
    for (int v = 0; v < VPL; ++v) {
        float bb = bias ? bias[c0 + v] : 0.f;
        ov[v] = fmaf(acc[v], inv, bb);
        if (RELU) ov[v] = fmaxf(ov[v], 0.f);
    }
    if (SOFTMAX) {
        float mm = ov[0];
#pragma unroll
        for (int v = 1; v < VPL; ++v) mm = fmaxf(mm, ov[v]);
#pragma unroll
        for (int o = 32; o; o >>= 1) mm = fmaxf(mm, __shfl_xor(mm, o, 64));
        float ss = 0.f;
#pragma unroll
        for (int v = 0; v < VPL; ++v) {
            ov[v] = __expf(ov[v] - mm);
            ss += ov[v];
        }
#pragma unroll
        for (int o = 32; o; o >>= 1) ss += __shfl_xor(ss, o, 64);
        float si = 1.f / ss;
#pragma unroll
        for (int v = 0; v < VPL; ++v) ov[v] *= si;
    }
    if (OUTH) {
        __half* op = (__half*)out + (size_t)node * C + c0;
        if (VPL == 4) {
            union { __half2 h2; unsigned u; } w0, w1;
            w0.h2 = __half2(__float2half(ov[0]), __float2half(ov[1]));
            w1.h2 = __half2(__float2half(ov[2]), __float2half(ov[3]));
            uint2 pk;
            pk.x = w0.u;
            pk.y = w1.u;
            *(uint2*)op = pk;
        } else {
            *(__half2*)op = __half2(__float2half(ov[0]), __float2half(ov[1]));
        }
    } else {
        float* op = out + (size_t)node * C + c0;
        if (VPL == 4)
            *(float4*)op = make_float4(ov[0], ov[1], ov[2], ov[3]);
        else
            *(float2*)op = make_float2(ov[0], ov[1]);
    }
}

// ---------------- launch ----------------

extern "C" void kernel_launch(void* const* d_in, const int* in_sizes, int n_in,
                              void* d_out, int out_size, void* d_ws, size_t ws_size,
                              hipStream_t stream) {
    const float* x = (const float*)d_in[0];
    const int* ei = (const int*)d_in[1];
    const float* W1 = (const float*)d_in[2];
    const float* a1s = (const float*)d_in[3];
    const float* a1d = (const float*)d_in[4];
    const float* b1 = (const float*)d_in[5];
    const float* W2 = (const float*)d_in[6];
    const float* a2s = (const float*)d_in[7];
    const float* a2d = (const float*)d_in[8];
    const float* b2 = (const float*)d_in[9];
    const float* W3 = (const float*)d_in[10];
    const float* a3s = (const float*)d_in[11];
    const float* a3d = (const float*)d_in[12];
    const float* b3 = (const float*)d_in[13];

    const int n = NN, E = EE;
    const int* src = ei;
    const int* dst = ei + E;

    char* base = (char*)d_ws;
    size_t o = 0;
    auto alloc = [&](size_t bytes) -> char* {
        char* p = base + o;
        o += (bytes + 255) & ~(size_t)255;
        return p;
    };
    int* off = (int*)alloc((n + 1) * sizeof(int));
    int* cur = (int*)alloc((n + 1) * sizeof(int));
    int* bsum = (int*)alloc(1024 * sizeof(int));
    int* es = (int*)alloc((size_t)E * sizeof(int));
    float* sbuf = (float*)alloc((size_t)2 * n * sizeof(float));  // ssrc | sdst
    float* ssrc = sbuf;
    float* sdst = sbuf + n;
    unsigned* gmu = (unsigned*)alloc(256);
    float* was = (float*)alloc(256 * sizeof(float));
    float* wad = (float*)alloc(256 * sizeof(float));
    short* W1h = (short*)alloc((size_t)DIN * HH * sizeof(short));
    short* W1l = (short*)alloc((size_t)DIN * HH * sizeof(short));
    short* W2h = (short*)alloc((size_t)HH * HH * sizeof(short));
    short* W2l = (short*)alloc((size_t)HH * HH * sizeof(short));
    short* W3h = (short*)alloc((size_t)HH * DOUT * sizeof(short));
    short* W3l = (short*)alloc((size_t)HH * DOUT * sizeof(short));
    __half* xh = (__half*)alloc((size_t)n * DIN * sizeof(__half));
    __half* Zh = (__half*)alloc((size_t)n * DIN * sizeof(__half));    // layer-1 Z (fp16)
    __half* Hh = (__half*)alloc((size_t)n * HH * sizeof(__half));     // per-layer H (fp16)
    __half* Abuf = (__half*)alloc((size_t)n * HH * sizeof(__half));   // fp16 inter-layer activations
    (void)ws_size;

    // --- CSR build (grouped by dst) ---
    hipMemsetAsync(cur, 0, (n + 1) * sizeof(int), stream);
    hist_kernel<<<(E + 255) / 256, 256, 0, stream>>>(dst, cur, E);
    int nb = (n + SCAN_B - 1) / SCAN_B;
    scan1_kernel<<<nb, SCAN_B, 0, stream>>>(cur, off, bsum, n);
    scan2_kernel<<<1, SCAN_B, 0, stream>>>(bsum, nb);
    scan3_kernel<<<nb, SCAN_B, 0, stream>>>(off, bsum, cur, n, E);
    scatter8_kernel<<<NCB * 8, 256, 0, stream>>>(src, dst, cur, es, E, n);

    // --- W splits + X fp16 copy ---
    wsplit_kernel<<<(DIN * HH + 255) / 256, 256, 0, stream>>>(W1, W1h, W1l, DIN, HH);
    wsplit_kernel<<<(HH * HH + 255) / 256, 256, 0, stream>>>(W2, W2h, W2l, HH, HH);
    wsplit_kernel<<<(HH * DOUT + 255) / 256, 256, 0, stream>>>(W3, W3h, W3l, HH, DOUT);
    tohalf_kernel<<<((n * DIN / 4) + 255) / 256, 256, 0, stream>>>(x, xh, (size_t)n * DIN);

    int wgrid = (n * 64 + 255) / 256;
    int agrid = (n + 3) / 4;
    int rb = (n + 127) / 128;

    // --- layer 1, reordered: logits via X@(W1 a); Z = A-hat X (fp16 gather -> fp16); A1 = relu(Z W1 + b1) -> fp16 ---
    {
        rowdots_kernel<<<(128 * 64 + 255) / 256, 256, 0, stream>>>(W1, a1s, a1d, was, wad, DIN, HH);
        rowdots_kernel<<<wgrid, 256, 0, stream>>>(x, was, wad, ssrc, sdst, n, DIN);
        hipMemsetAsync(gmu, 0, 4, stream);
        gmax_kernel<<<64, 256, 0, stream>>>(ssrc, gmu, n);
        aggf_kernel<DIN, false, false, true><<<agrid, 256, 0, stream>>>(xh, ssrc, sdst, off, es, nullptr, (float*)Zh,
                                                                        gmu, n);
        dim3 g(HH / 128, rb);
        gemm_mfma_kernel<true, false, true, true><<<g, 256, 0, stream>>>((const float*)Zh, W1h, W1l, b1,
                                                                         (float*)Abuf, nullptr, nullptr, nullptr,
                                                                         nullptr, n, DIN, HH);
    }
    // --- layers 2,3 (shared W2): gemm(fp16 A-in, fp16 H-out + fused dots), single-pass agg -> fp16 Abuf ---
    for (int t = 0; t < 2; ++t) {
        dim3 g(HH / 128, rb);
        hipMemsetAsync(sbuf, 0, (size_t)2 * n * sizeof(float), stream);
        hipMemsetAsync(gmu, 0, 4, stream);
        gemm_mfma_kernel<false, true, true, true><<<g, 256, 0, stream>>>((const float*)Abuf, W2h, W2l, nullptr,
                                                                         (float*)Hh, a2s, a2d, ssrc, sdst, n, HH, HH);
        gmax_kernel<<<64, 256, 0, stream>>>(ssrc, gmu, n);
        aggf_kernel<HH, true, false, true><<<agrid, 256, 0, stream>>>(Hh, ssrc, sdst, off, es, b2, (float*)Abuf, gmu,
                                                                      n);
    }
    // --- layer 4: gemm(fp16 A-in, fp16 H-out + fused dots), single-pass agg + feature softmax -> d_out (fp32) ---
    {
        dim3 g(DOUT / 128, rb);
        hipMemsetAsync(sbuf, 0, (size_t)2 * n * sizeof(float), stream);
        hipMemsetAsync(gmu, 0, 4, stream);
        gemm_mfma_kernel<false, true, true, true><<<g, 256, 0, stream>>>((const float*)Abuf, W3h, W3l, nullptr,
                                                                         (float*)Hh, a3s, a3d, ssrc, sdst, n, HH,
                                                                         DOUT);
        gmax_kernel<<<64, 256, 0, stream>>>(ssrc, gmu, n);
        aggf_kernel<DOUT, false, true, false><<<agrid, 256, 0, stream>>>(Hh, ssrc, sdst, off, es, b3, (float*)d_out,
                                                                         gmu, n);
    }
}

// Round 13
// 628.891 us; speedup vs baseline: 1.3315x; 1.0595x over previous
//
#include <hip/hip_runtime.h>
#include <hip/hip_bf16.h>
#include <hip/hip_fp16.h>

#define NN 50000
#define EE 1600000
#define DIN 128
#define HH 256
#define DOUT 128
#define MHAT 20.0f  // static softmax shift: valid for any true logit max in (-67, 108); hard bound here ~9

typedef __attribute__((ext_vector_type(8))) short short8;
typedef __attribute__((ext_vector_type(4))) float f32x4;

__device__ __forceinline__ short f2bf(float v) {
    union { float f; unsigned u; } a;
    a.f = v;
    unsigned r = a.u + 0x7fffu + ((a.u >> 16) & 1u);  // RTNE
    return (short)(r >> 16);
}
__device__ __forceinline__ float bf2f(short h) {
    union { unsigned u; float f; } a;
    a.u = ((unsigned)(unsigned short)h) << 16;
    return a.f;
}

// ---------------- CSR build ----------------

__global__ __launch_bounds__(256) void hist_kernel(const int* __restrict__ dst, int* __restrict__ deg, int E) {
    int e = blockIdx.x * 256 + threadIdx.x;
    if (e < E) atomicAdd(&deg[dst[e]], 1);
}

#define SCAN_B 256

__global__ __launch_bounds__(SCAN_B) void scan1_kernel(const int* __restrict__ deg, int* __restrict__ exc,
                                                       int* __restrict__ bsum, int n) {
    __shared__ int tmp[SCAN_B];
    int i = blockIdx.x * SCAN_B + threadIdx.x;
    int v = (i < n) ? deg[i] : 0;
    tmp[threadIdx.x] = v;
    __syncthreads();
    for (int o = 1; o < SCAN_B; o <<= 1) {
        int t = (threadIdx.x >= o) ? tmp[threadIdx.x - o] : 0;
        __syncthreads();
        tmp[threadIdx.x] += t;
        __syncthreads();
    }
    if (i < n) exc[i] = tmp[threadIdx.x] - v;
    if (threadIdx.x == SCAN_B - 1) bsum[blockIdx.x] = tmp[SCAN_B - 1];
}

__global__ __launch_bounds__(SCAN_B) void scan2_kernel(int* __restrict__ bsum, int nb) {
    __shared__ int tmp[SCAN_B];
    int v = (threadIdx.x < nb) ? bsum[threadIdx.x] : 0;
    tmp[threadIdx.x] = v;
    __syncthreads();
    for (int o = 1; o < SCAN_B; o <<= 1) {
        int t = (threadIdx.x >= o) ? tmp[threadIdx.x - o] : 0;
        __syncthreads();
        tmp[threadIdx.x] += t;
        __syncthreads();
    }
    if (threadIdx.x < nb) bsum[threadIdx.x] = tmp[threadIdx.x] - v;
}

__global__ __launch_bounds__(SCAN_B) void scan3_kernel(int* __restrict__ exc, const int* __restrict__ bsum,
                                                       int* __restrict__ cursor, int n, int E) {
    int i = blockIdx.x * SCAN_B + threadIdx.x;
    if (i < n) {
        int v = exc[i] + bsum[blockIdx.x];
        exc[i] = v;
        cursor[i] = v;
    }
    if (i == n) exc[n] = E;
}

#define NCB 256

__global__ __launch_bounds__(256) void scatter8_kernel(const int* __restrict__ src, const int* __restrict__ dst,
                                                       int* __restrict__ cursor, int* __restrict__ es, int E, int n) {
    int q = blockIdx.x & 7;
    int cb = blockIdx.x >> 3;
    int lo = q * (n >> 3);
    int hi = (q == 7) ? n : lo + (n >> 3);
    int chunk = (E + NCB - 1) / NCB;
    int e1 = min((cb + 1) * chunk, E);
    for (int e = cb * chunk + threadIdx.x; e < e1; e += 256) {
        int d = dst[e];
        if (d >= lo && d < hi) {
            int pos = atomicAdd(&cursor[d], 1);
            es[pos] = src[e];
        }
    }
}

// ---------------- merged W pre-split (W1|W2|W3 -> transposed bf16 hi/lo) ----------------

__global__ __launch_bounds__(256) void wsplit3_kernel(const float* __restrict__ W1, const float* __restrict__ W2,
                                                      const float* __restrict__ W3, short* __restrict__ W1h,
                                                      short* __restrict__ W1l, short* __restrict__ W2h,
                                                      short* __restrict__ W2l, short* __restrict__ W3h,
                                                      short* __restrict__ W3l) {
    int f = blockIdx.x * 256 + threadIdx.x;
    const float* W;
    short *Wh, *Wl;
    int K, C, idx;
    if (f < DIN * HH) {
        W = W1; Wh = W1h; Wl = W1l; K = DIN; C = HH; idx = f;
    } else if (f < DIN * HH + HH * HH) {
        W = W2; Wh = W2h; Wl = W2l; K = HH; C = HH; idx = f - DIN * HH;
    } else if (f < DIN * HH + HH * HH + HH * DOUT) {
        W = W3; Wh = W3h; Wl = W3l; K = HH; C = DOUT; idx = f - DIN * HH - HH * HH;
    } else {
        return;
    }
    int k = idx / C, c = idx % C;
    float v = W[idx];
    short h = f2bf(v);
    short l = f2bf(v - bf2f(h));
    Wh[(size_t)c * K + k] = h;
    Wl[(size_t)c * K + k] = l;
}

// ---------------- layer-1 x prep: xh = fp16(x), ssrc = x.was, sdst = x.wad (one x pass) ----------------

__global__ __launch_bounds__(256) void xprep_kernel(const float* __restrict__ x, __half* __restrict__ xh,
                                                    const float* __restrict__ was, const float* __restrict__ wad,
                                                    float* __restrict__ s1, float* __restrict__ s2, int n) {
    int w = (blockIdx.x * 256 + threadIdx.x) >> 6;
    int lane = threadIdx.x & 63;
    if (w >= n) return;
    const float* xp = x + (size_t)w * DIN + lane * 2;
    float2 v = *(const float2*)xp;
    *(__half2*)(xh + (size_t)w * DIN + lane * 2) = __half2(__float2half(v.x), __float2half(v.y));
    float d1 = v.x * was[lane * 2] + v.y * was[lane * 2 + 1];
    float d2 = v.x * wad[lane * 2] + v.y * wad[lane * 2 + 1];
#pragma unroll
    for (int o = 32; o; o >>= 1) {
        d1 += __shfl_xor(d1, o, 64);
        d2 += __shfl_xor(d2, o, 64);
    }
    if (lane == 0) {
        s1[w] = d1;
        s2[w] = d2;
    }
}

// ---------------- split-bf16 MFMA GEMM (+fused dots; fp32 or fp16 A-in; fp32 or fp16 out) ----------------

template <bool BRELU, bool DOTS, bool HOUT, bool AHIN>
__global__ __launch_bounds__(256) void gemm_mfma_kernel(const float* __restrict__ X, const short* __restrict__ BhT,
                                                        const short* __restrict__ BlT, const float* __restrict__ bias,
                                                        float* __restrict__ out, const float* __restrict__ a1v,
                                                        const float* __restrict__ a2v, float* __restrict__ s1,
                                                        float* __restrict__ s2, int n, int K, int Cout) {
    __shared__ short Ah[128][40], Al[128][40];
    __shared__ short Bh[128][40], Bl[128][40];
    int tid = threadIdx.x;
    int row0 = blockIdx.y * 128, col0 = blockIdx.x * 128;
    int lane = tid & 63, wid = tid >> 6;
    int wr = (wid >> 1) * 64, wc = (wid & 1) * 64;

    f32x4 acc[4][4];
#pragma unroll
    for (int mi = 0; mi < 4; ++mi)
#pragma unroll
        for (int ni = 0; ni < 4; ++ni) acc[mi][ni] = 0.f;

    int srow = tid >> 1;
    int sk = (tid & 1) * 16;

    for (int k0 = 0; k0 < K; k0 += 32) {
        {
            float v[16];
            int gr = row0 + srow;
            if (gr < n) {
                if (AHIN) {
                    const __half* p = (const __half*)X + (size_t)gr * K + k0 + sk;
                    uint4 r0 = ((const uint4*)p)[0];
                    uint4 r1 = ((const uint4*)p)[1];
                    unsigned w[8] = {r0.x, r0.y, r0.z, r0.w, r1.x, r1.y, r1.z, r1.w};
#pragma unroll
                    for (int j = 0; j < 8; ++j) {
                        union { unsigned u; __half2 h; } c;
                        c.u = w[j];
                        float2 f = __half22float2(c.h);
                        v[2 * j] = f.x;
                        v[2 * j + 1] = f.y;
                    }
                } else {
                    const float* p = X + (size_t)gr * K + k0 + sk;
                    float4 f0 = ((const float4*)p)[0];
                    float4 f1 = ((const float4*)p)[1];
                    float4 f2 = ((const float4*)p)[2];
                    float4 f3 = ((const float4*)p)[3];
                    v[0] = f0.x; v[1] = f0.y; v[2] = f0.z; v[3] = f0.w;
                    v[4] = f1.x; v[5] = f1.y; v[6] = f1.z; v[7] = f1.w;
                    v[8] = f2.x; v[9] = f2.y; v[10] = f2.z; v[11] = f2.w;
                    v[12] = f3.x; v[13] = f3.y; v[14] = f3.z; v[15] = f3.w;
                }
            } else {
#pragma unroll
                for (int j = 0; j < 16; ++j) v[j] = 0.f;
            }
            short8 h0, h1, l0, l1;
#pragma unroll
            for (int j = 0; j < 8; ++j) {
                short h = f2bf(v[j]);
                h0[j] = h;
                l0[j] = f2bf(v[j] - bf2f(h));
            }
#pragma unroll
            for (int j = 0; j < 8; ++j) {
                short h = f2bf(v[8 + j]);
                h1[j] = h;
                l1[j] = f2bf(v[8 + j] - bf2f(h));
            }
            *(short8*)&Ah[srow][sk] = h0;
            *(short8*)&Ah[srow][sk + 8] = h1;
            *(short8*)&Al[srow][sk] = l0;
            *(short8*)&Al[srow][sk + 8] = l1;
        }
        {
            const short* ph = BhT + (size_t)(col0 + srow) * K + k0 + sk;
            const short* pl = BlT + (size_t)(col0 + srow) * K + k0 + sk;
            short8 bh0 = ((const short8*)ph)[0];
            short8 bh1 = ((const short8*)ph)[1];
            short8 bl0 = ((const short8*)pl)[0];
            short8 bl1 = ((const short8*)pl)[1];
            *(short8*)&Bh[srow][sk] = bh0;
            *(short8*)&Bh[srow][sk + 8] = bh1;
            *(short8*)&Bl[srow][sk] = bl0;
            *(short8*)&Bl[srow][sk + 8] = bl1;
        }
        __syncthreads();

        int fr = lane & 15, kb = lane >> 4;
        short8 a_h[4], a_l[4];
#pragma unroll
        for (int mi = 0; mi < 4; ++mi) {
            a_h[mi] = *(const short8*)&Ah[wr + mi * 16 + fr][kb * 8];
            a_l[mi] = *(const short8*)&Al[wr + mi * 16 + fr][kb * 8];
        }
#pragma unroll
        for (int ni = 0; ni < 4; ++ni) {
            short8 b_h = *(const short8*)&Bh[wc + ni * 16 + fr][kb * 8];
            short8 b_l = *(const short8*)&Bl[wc + ni * 16 + fr][kb * 8];
#pragma unroll
            for (int mi = 0; mi < 4; ++mi) {
                acc[mi][ni] = __builtin_amdgcn_mfma_f32_16x16x32_bf16(a_l[mi], b_h, acc[mi][ni], 0, 0, 0);
                acc[mi][ni] = __builtin_amdgcn_mfma_f32_16x16x32_bf16(a_h[mi], b_l, acc[mi][ni], 0, 0, 0);
                acc[mi][ni] = __builtin_amdgcn_mfma_f32_16x16x32_bf16(a_h[mi], b_h, acc[mi][ni], 0, 0, 0);
            }
        }
        __syncthreads();
    }

    int dc = lane & 15, dr = (lane >> 4) * 4;

    if (DOTS) {
#pragma unroll
        for (int mi = 0; mi < 4; ++mi) {
#pragma unroll
            for (int r = 0; r < 4; ++r) {
                float p1 = 0.f, p2 = 0.f;
#pragma unroll
                for (int ni = 0; ni < 4; ++ni) {
                    int gcol = col0 + wc + ni * 16 + dc;
                    float v = acc[mi][ni][r];
                    p1 = fmaf(v, a1v[gcol], p1);
                    p2 = fmaf(v, a2v[gcol], p2);
                }
#pragma unroll
                for (int o = 8; o; o >>= 1) {
                    p1 += __shfl_xor(p1, o, 64);
                    p2 += __shfl_xor(p2, o, 64);
                }
                int grow = row0 + wr + mi * 16 + dr + r;
                if (dc == 0 && grow < n) {
                    atomicAdd(s1 + grow, p1);
                    atomicAdd(s2 + grow, p2);
                }
            }
        }
    }

#pragma unroll
    for (int mi = 0; mi < 4; ++mi) {
#pragma unroll
        for (int r = 0; r < 4; ++r) {
            int grow = row0 + wr + mi * 16 + dr + r;
            if (grow >= n) continue;
#pragma unroll
            for (int ni = 0; ni < 4; ++ni) {
                int gcol = col0 + wc + ni * 16 + dc;
                float v = acc[mi][ni][r];
                if (BRELU) {
                    v += bias[gcol];
                    v = fmaxf(v, 0.f);
                }
                if (HOUT) {
                    ((__half*)out)[(size_t)grow * Cout + gcol] = __float2half(v);
                } else {
                    out[(size_t)grow * Cout + gcol] = v;
                }
            }
        }
    }
}

// ---------------- per-row dual dot (W1 projection only, n=128 rows) ----------------

__global__ __launch_bounds__(256) void rowdots_kernel(const float* __restrict__ H, const float* __restrict__ a1,
                                                      const float* __restrict__ a2, float* __restrict__ s1,
                                                      float* __restrict__ s2, int n, int C) {
    int w = (blockIdx.x * 256 + threadIdx.x) >> 6;
    int lane = threadIdx.x & 63;
    if (w >= n) return;
    const float* hp = H + (size_t)w * C;
    float acc1 = 0.f, acc2 = 0.f;
    for (int c = lane; c < C; c += 64) {
        float hv = hp[c];
        acc1 = fmaf(hv, a1[c], acc1);
        acc2 = fmaf(hv, a2[c], acc2);
    }
#pragma unroll
    for (int o = 32; o; o >>= 1) {
        acc1 += __shfl_xor(acc1, o, 64);
        acc2 += __shfl_xor(acc2, o, 64);
    }
    if (lane == 0) {
        s1[w] = acc1;
        s2[w] = acc2;
    }
}

// ---------------- fused aggregation: single-pass (static shift MHAT) + 8B/lane gather, 1 wave/node ----------------
// softmax shift-invariance: any m-hat with (max logit - m-hat) in (-87, 88) gives exact alpha ratios in fp32.

template <int C, bool RELU, bool SOFTMAX, bool OUTH>
__global__ __launch_bounds__(256) void aggf_kernel(const __half* __restrict__ H, const float* __restrict__ ssrc,
                                                   const float* __restrict__ sdst, const int* __restrict__ off,
                                                   const int* __restrict__ es, const float* __restrict__ bias,
                                                   float* __restrict__ out, int n) {
    constexpr int VPL = C / 64;
    int wid = threadIdx.x >> 6, lane = threadIdx.x & 63;
    int node = blockIdx.x * 4 + wid;
    if (node >= n) return;
    int beg = off[node], end = off[node + 1];
    float sd = sdst[node];

    float acc[VPL];
#pragma unroll
    for (int v = 0; v < VPL; ++v) acc[v] = 0.f;
    float den = 0.f;
    int c0 = lane * VPL;

    for (int base = beg; base < end; base += 64) {
        int e = base + lane;
        float p = 0.f;
        int s = 0;
        if (e < end) {
            s = es[e];
            float g = ssrc[s] + sd;
            g = (g > 0.f) ? g : 0.2f * g;
            p = __expf(g - MHAT);
            den += p;
        }
        int cnt = end - base;
        if (cnt > 64) cnt = 64;
        int j0 = 0;
        for (; j0 + 8 <= cnt; j0 += 8) {
            float pj[8];
            const __half* hp[8];
#pragma unroll
            for (int u = 0; u < 8; ++u) {
                pj[u] = __shfl(p, j0 + u, 64);
                int sj = __shfl(s, j0 + u, 64);
                hp[u] = H + (size_t)sj * C + c0;
            }
            if (VPL == 4) {
                uint2 raw[8];
#pragma unroll
                for (int u = 0; u < 8; ++u) raw[u] = *(const uint2*)hp[u];
#pragma unroll
                for (int u = 0; u < 8; ++u) {
                    union { unsigned u32; __half2 h2; } lo, hi;
                    lo.u32 = raw[u].x;
                    hi.u32 = raw[u].y;
                    float2 f0 = __half22float2(lo.h2);
                    float2 f1 = __half22float2(hi.h2);
                    acc[0] = fmaf(pj[u], f0.x, acc[0]);
                    acc[1] = fmaf(pj[u], f0.y, acc[1]);
                    acc[2] = fmaf(pj[u], f1.x, acc[2]);
                    acc[3] = fmaf(pj[u], f1.y, acc[3]);
                }
            } else {
                __half2 hv[8];
#pragma unroll
                for (int u = 0; u < 8; ++u) hv[u] = *(const __half2*)hp[u];
#pragma unroll
                for (int u = 0; u < 8; ++u) {
                    float2 f = __half22float2(hv[u]);
                    acc[0] = fmaf(pj[u], f.x, acc[0]);
                    acc[1] = fmaf(pj[u], f.y, acc[1]);
                }
            }
        }
        for (; j0 < cnt; ++j0) {
            float pj = __shfl(p, j0, 64);
            int sj = __shfl(s, j0, 64);
            const __half* hp = H + (size_t)sj * C + c0;
            if (VPL == 4) {
                uint2 raw = *(const uint2*)hp;
                union { unsigned u32; __half2 h2; } lo, hi;
                lo.u32 = raw.x;
                hi.u32 = raw.y;
                float2 f0 = __half22float2(lo.h2);
                float2 f1 = __half22float2(hi.h2);
                acc[0] = fmaf(pj, f0.x, acc[0]);
                acc[1] = fmaf(pj, f0.y, acc[1]);
                acc[2] = fmaf(pj, f1.x, acc[2]);
                acc[3] = fmaf(pj, f1.y, acc[3]);
            } else {
                float2 f = __half22float2(*(const __half2*)hp);
                acc[0] = fmaf(pj, f.x, acc[0]);
                acc[1] = fmaf(pj, f.y, acc[1]);
            }
        }
    }

#pragma unroll
    for (int o = 32; o; o >>= 1) den += __shfl_xor(den, o, 64);
    float inv = (den > 0.f) ? 1.f / den : 0.f;

    float ov[VPL];
#pragma unroll
    for (int v = 0; v < VPL; ++v) {
        float bb = bias ? bias[c0 + v] : 0.f;
        ov[v] = fmaf(acc[v], inv, bb);
        if (RELU) ov[v] = fmaxf(ov[v], 0.f);
    }
    if (SOFTMAX) {
        float mm = ov[0];
#pragma unroll
        for (int v = 1; v < VPL; ++v) mm = fmaxf(mm, ov[v]);
#pragma unroll
        for (int o = 32; o; o >>= 1) mm = fmaxf(mm, __shfl_xor(mm, o, 64));
        float ss = 0.f;
#pragma unroll
        for (int v = 0; v < VPL; ++v) {
            ov[v] = __expf(ov[v] - mm);
            ss += ov[v];
        }
#pragma unroll
        for (int o = 32; o; o >>= 1) ss += __shfl_xor(ss, o, 64);
        float si = 1.f / ss;
#pragma unroll
        for (int v = 0; v < VPL; ++v) ov[v] *= si;
    }
    if (OUTH) {
        __half* op = (__half*)out + (size_t)node * C + c0;
        if (VPL == 4) {
            union { __half2 h2; unsigned u; } w0, w1;
            w0.h2 = __half2(__float2half(ov[0]), __float2half(ov[1]));
            w1.h2 = __half2(__float2half(ov[2]), __float2half(ov[3]));
            uint2 pk;
            pk.x = w0.u;
            pk.y = w1.u;
            *(uint2*)op = pk;
        } else {
            *(__half2*)op = __half2(__float2half(ov[0]), __float2half(ov[1]));
        }
    } else {
        float* op = out + (size_t)node * C + c0;
        if (VPL == 4)
            *(float4*)op = make_float4(ov[0], ov[1], ov[2], ov[3]);
        else
            *(float2*)op = make_float2(ov[0], ov[1]);
    }
}

// ---------------- launch ----------------

extern "C" void kernel_launch(void* const* d_in, const int* in_sizes, int n_in,
                              void* d_out, int out_size, void* d_ws, size_t ws_size,
                              hipStream_t stream) {
    const float* x = (const float*)d_in[0];
    const int* ei = (const int*)d_in[1];
    const float* W1 = (const float*)d_in[2];
    const float* a1s = (const float*)d_in[3];
    const float* a1d = (const float*)d_in[4];
    const float* b1 = (const float*)d_in[5];
    const float* W2 = (const float*)d_in[6];
    const float* a2s = (const float*)d_in[7];
    const float* a2d = (const float*)d_in[8];
    const float* b2 = (const float*)d_in[9];
    const float* W3 = (const float*)d_in[10];
    const float* a3s = (const float*)d_in[11];
    const float* a3d = (const float*)d_in[12];
    const float* b3 = (const float*)d_in[13];

    const int n = NN, E = EE;
    const int* src = ei;
    const int* dst = ei + E;

    char* base = (char*)d_ws;
    size_t o = 0;
    auto alloc = [&](size_t bytes) -> char* {
        char* p = base + o;
        o += (bytes + 255) & ~(size_t)255;
        return p;
    };
    int* off = (int*)alloc((n + 1) * sizeof(int));
    int* cur = (int*)alloc((n + 1) * sizeof(int));
    int* bsum = (int*)alloc(1024 * sizeof(int));
    int* es = (int*)alloc((size_t)E * sizeof(int));
    float* sbuf = (float*)alloc((size_t)2 * n * sizeof(float));  // ssrc | sdst
    float* ssrc = sbuf;
    float* sdst = sbuf + n;
    float* was = (float*)alloc(256 * sizeof(float));
    float* wad = (float*)alloc(256 * sizeof(float));
    short* W1h = (short*)alloc((size_t)DIN * HH * sizeof(short));
    short* W1l = (short*)alloc((size_t)DIN * HH * sizeof(short));
    short* W2h = (short*)alloc((size_t)HH * HH * sizeof(short));
    short* W2l = (short*)alloc((size_t)HH * HH * sizeof(short));
    short* W3h = (short*)alloc((size_t)HH * DOUT * sizeof(short));
    short* W3l = (short*)alloc((size_t)HH * DOUT * sizeof(short));
    __half* xh = (__half*)alloc((size_t)n * DIN * sizeof(__half));
    __half* Zh = (__half*)alloc((size_t)n * DIN * sizeof(__half));   // layer-1 Z (fp16)
    __half* Hh = (__half*)alloc((size_t)n * HH * sizeof(__half));    // per-layer H (fp16)
    __half* Abuf = (__half*)alloc((size_t)n * HH * sizeof(__half));  // fp16 inter-layer activations
    (void)ws_size;

    // --- CSR build (grouped by dst) ---
    hipMemsetAsync(cur, 0, (n + 1) * sizeof(int), stream);
    hist_kernel<<<(E + 255) / 256, 256, 0, stream>>>(dst, cur, E);
    int nb = (n + SCAN_B - 1) / SCAN_B;
    scan1_kernel<<<nb, SCAN_B, 0, stream>>>(cur, off, bsum, n);
    scan2_kernel<<<1, SCAN_B, 0, stream>>>(bsum, nb);
    scan3_kernel<<<nb, SCAN_B, 0, stream>>>(off, bsum, cur, n, E);
    scatter8_kernel<<<NCB * 8, 256, 0, stream>>>(src, dst, cur, es, E, n);

    // --- W splits (merged) ---
    int wtot = DIN * HH + HH * HH + HH * DOUT;
    wsplit3_kernel<<<(wtot + 255) / 256, 256, 0, stream>>>(W1, W2, W3, W1h, W1l, W2h, W2l, W3h, W3l);

    int wgrid = (n * 64 + 255) / 256;
    int agrid = (n + 3) / 4;
    int rb = (n + 127) / 128;

    // --- layer 1, reordered: logits via X@(W1 a); Z = A-hat X (fp16 gather -> fp16); A1 = relu(Z W1 + b1) -> fp16 ---
    {
        rowdots_kernel<<<(128 * 64 + 255) / 256, 256, 0, stream>>>(W1, a1s, a1d, was, wad, DIN, HH);
        xprep_kernel<<<wgrid, 256, 0, stream>>>(x, xh, was, wad, ssrc, sdst, n);
        aggf_kernel<DIN, false, false, true><<<agrid, 256, 0, stream>>>(xh, ssrc, sdst, off, es, nullptr, (float*)Zh,
                                                                        n);
        dim3 g(HH / 128, rb);
        gemm_mfma_kernel<true, false, true, true><<<g, 256, 0, stream>>>((const float*)Zh, W1h, W1l, b1,
                                                                         (float*)Abuf, nullptr, nullptr, nullptr,
                                                                         nullptr, n, DIN, HH);
    }
    // --- layers 2,3 (shared W2): gemm(fp16 A-in, fp16 H-out + fused dots), single-pass agg -> fp16 Abuf ---
    for (int t = 0; t < 2; ++t) {
        dim3 g(HH / 128, rb);
        hipMemsetAsync(sbuf, 0, (size_t)2 * n * sizeof(float), stream);
        gemm_mfma_kernel<false, true, true, true><<<g, 256, 0, stream>>>((const float*)Abuf, W2h, W2l, nullptr,
                                                                         (float*)Hh, a2s, a2d, ssrc, sdst, n, HH, HH);
        aggf_kernel<HH, true, false, true><<<agrid, 256, 0, stream>>>(Hh, ssrc, sdst, off, es, b2, (float*)Abuf, n);
    }
    // --- layer 4: gemm(fp16 A-in, fp16 H-out + fused dots), single-pass agg + feature softmax -> d_out (fp32) ---
    {
        dim3 g(DOUT / 128, rb);
        hipMemsetAsync(sbuf, 0, (size_t)2 * n * sizeof(float), stream);
        gemm_mfma_kernel<false, true, true, true><<<g, 256, 0, stream>>>((const float*)Abuf, W3h, W3l, nullptr,
                                                                         (float*)Hh, a3s, a3d, ssrc, sdst, n, HH,
                                                                         DOUT);
        aggf_kernel<DOUT, false, true, false><<<agrid, 256, 0, stream>>>(Hh, ssrc, sdst, off, es, b3, (float*)d_out,
                                                                         n);
    }
}